// Round 1
// baseline (16092.883 us; speedup 1.0000x reference)
//
#include <hip/hip_runtime.h>

typedef _Float16 half8 __attribute__((ext_vector_type(8)));
typedef _Float16 half4_t __attribute__((ext_vector_type(4)));
typedef float f32x4 __attribute__((ext_vector_type(4)));

#define SCALE 0.03125f   // 1/sqrt(1024)

// workspace layout (bytes)
#define XZ_OFF   0ULL            // f16 [8192][2048]  33,554,432
#define XBF_OFF  33554432ULL     // f16 [8192][1024]  16,777,216
#define WXZ_OFF  50331648ULL     // f16 [2048][1024]   4,194,304
#define WH_OFF   54525952ULL     // f16 [1024][1024]   2,097,152
#define WW_OFF   56623104ULL     // f16 [1024][1024]   2,097,152
#define HG_OFF   58720256ULL     // f16 [2][16][1024]     65,536 (double buffer)
#define WSP_OFF  58785792ULL     // f32 [32][256]         32,768
#define AP_OFF   58818560ULL     // f32 [32][256]         32,768
#define CP_OFF   58851328ULL     // f32 [32][16]           2,048
#define TAG_OFF  58853376ULL     // u32 [2][32]              256

__global__ void cvt_kernel(const float* __restrict__ in, _Float16* __restrict__ o, int n4) {
    int i = blockIdx.x * 256 + threadIdx.x;
    if (i < n4) {
        f32x4 v = ((const f32x4*)in)[i];
        half4_t h;
        h[0] = (_Float16)v[0]; h[1] = (_Float16)v[1];
        h[2] = (_Float16)v[2]; h[3] = (_Float16)v[3];
        ((half4_t*)o)[i] = h;
    }
}

// xz[m][n] = sum_k x[m][k] * Wxz[n][k];  M=8192, N=2048, K=1024
__launch_bounds__(256, 1)
__global__ void gemm_xz(const _Float16* __restrict__ A,   // [8192][1024]
                        const _Float16* __restrict__ Bw,  // [2048][1024]
                        _Float16* __restrict__ C) {       // [8192][2048]
    __shared__ _Float16 As[128 * 40];
    __shared__ _Float16 Bs[128 * 40];
    const int tid = threadIdx.x;
    const int m0 = blockIdx.y * 128, n0 = blockIdx.x * 128;
    const int w = tid >> 6, lane = tid & 63;
    const int mw = (w >> 1) * 64, nw = (w & 1) * 64;
    const int row = lane & 15, q = lane >> 4;
    f32x4 acc[4][4];
    #pragma unroll
    for (int mt = 0; mt < 4; mt++)
        #pragma unroll
        for (int nt = 0; nt < 4; nt++)
            acc[mt][nt] = (f32x4){0.f, 0.f, 0.f, 0.f};

    for (int k0 = 0; k0 < 1024; k0 += 32) {
        __syncthreads();
        for (int cc = tid; cc < 512; cc += 256) {
            int r = cc >> 2, kc = (cc & 3) * 8;
            *(half8*)(&As[r * 40 + kc]) = *(const half8*)(&A[(size_t)(m0 + r) * 1024 + k0 + kc]);
            *(half8*)(&Bs[r * 40 + kc]) = *(const half8*)(&Bw[(size_t)(n0 + r) * 1024 + k0 + kc]);
        }
        __syncthreads();
        half8 af[4], bf[4];
        #pragma unroll
        for (int mt = 0; mt < 4; mt++) af[mt] = *(const half8*)(&As[(mw + mt * 16 + row) * 40 + q * 8]);
        #pragma unroll
        for (int nt = 0; nt < 4; nt++) bf[nt] = *(const half8*)(&Bs[(nw + nt * 16 + row) * 40 + q * 8]);
        #pragma unroll
        for (int mt = 0; mt < 4; mt++)
            #pragma unroll
            for (int nt = 0; nt < 4; nt++)
                acc[mt][nt] = __builtin_amdgcn_mfma_f32_16x16x32_f16(af[mt], bf[nt], acc[mt][nt], 0, 0, 0);
    }
    #pragma unroll
    for (int mt = 0; mt < 4; mt++)
        #pragma unroll
        for (int nt = 0; nt < 4; nt++)
            #pragma unroll
            for (int r = 0; r < 4; r++) {
                int gm = m0 + mw + mt * 16 + q * 4 + r;
                int gn = n0 + nw + nt * 16 + row;
                C[(size_t)gm * 2048 + gn] = (_Float16)acc[mt][nt][r];
            }
}

// Persistent scan: 32 blocks, block s owns columns [s*32, s*32+32) for all 16 batches.
__launch_bounds__(256, 1)
__global__ void scan_kernel(const _Float16* __restrict__ xz,   // [8192][2048]
                            const float* __restrict__ tape_in, // [16][16][1024]
                            const float* __restrict__ h_in,    // [16][1024]
                            const float* __restrict__ bh,      // [1024]
                            const _Float16* __restrict__ wh,   // [1024][1024]
                            const _Float16* __restrict__ ww,   // [1024][1024]
                            _Float16* __restrict__ hg,         // [2][16][1024]
                            float* __restrict__ wsp,           // [32][256]
                            float* __restrict__ ap,            // [32][256]
                            float* __restrict__ cp,            // [32][16]
                            unsigned* __restrict__ tags,       // [2][32]
                            float* __restrict__ out) {
    __shared__ _Float16 h_l[16 * 1032];
    __shared__ float tape_l[256 * 33];
    __shared__ float wv_l[16 * 33];
    __shared__ float hn_l[16 * 33];
    __shared__ float rv_l[16 * 33];
    __shared__ float red_l[8 * 256];
    __shared__ float wa_l[256], ra_l[256], c_l[16];

    const int tid = threadIdx.x, s = blockIdx.x;
    const int w = tid >> 6, lane = tid & 63;
    const int bi = tid >> 4, ni = tid & 15;   // (batch, slot) mapping
    const int ci = tid & 31, gi = tid >> 5;   // (col, group) mapping
    unsigned* tag_p1 = tags;
    unsigned* tag_p2 = tags + 32;

    // ---- W fragment preload (pinned in VGPRs for all 512 steps) ----
    half8 whf[2][8], wwf[2][8];
    {
        const int fr = lane & 15, fq = lane >> 4;
        #pragma unroll
        for (int nt = 0; nt < 2; nt++)
            #pragma unroll
            for (int kk = 0; kk < 8; kk++) {
                int gcol = s * 32 + nt * 16 + fr;
                int gk = w * 256 + kk * 32 + fq * 8;
                whf[nt][kk] = *(const half8*)(&wh[(size_t)gcol * 1024 + gk]);
                wwf[nt][kk] = *(const half8*)(&ww[(size_t)gcol * 1024 + gk]);
            }
    }
    // ---- prologue: tape slice -> LDS, publish h_init (buffer 0), A partials ----
    for (int j = 0; j < 32; j++) {
        int bn = gi + (j << 3);
        tape_l[bn * 33 + ci] = tape_in[(size_t)bn * 1024 + s * 32 + ci];
    }
    for (int j = 0; j < 2; j++) {
        int b2 = gi + (j << 3);
        hg[(size_t)b2 * 1024 + s * 32 + ci] = (_Float16)h_in[(size_t)b2 * 1024 + s * 32 + ci];
    }
    __syncthreads();
    {
        float asum = 0.f;
        for (int c2 = 0; c2 < 32; c2++)
            asum += h_in[(size_t)bi * 1024 + s * 32 + c2] * tape_l[tid * 33 + c2];
        ap[s * 256 + tid] = asum;
    }
    __threadfence();
    __syncthreads();
    if (tid == 0) __hip_atomic_store(&tag_p2[s], 1u, __ATOMIC_RELEASE, __HIP_MEMORY_SCOPE_AGENT);

    for (int t = 0; t < 512; t++) {
        // ================= Phase 1: h_t, out_t =================
        if (tid < 32) {
            while (__hip_atomic_load(&tag_p2[tid], __ATOMIC_RELAXED, __HIP_MEMORY_SCOPE_AGENT) < (unsigned)(t + 1))
                __builtin_amdgcn_s_sleep(1);
        }
        __syncthreads();
        __threadfence();

        // scalar stage: sum partials, softmaxes (thread = (batch bi, slot ni))
        float wa = 0.f, rs;
        {
            float wsum = 0.f, asum = 0.f;
            if (t > 0)
                for (int s2 = 0; s2 < 32; s2++) wsum += wsp[s2 * 256 + tid];
            for (int s2 = 0; s2 < 32; s2++) asum += ap[s2 * 256 + tid];
            if (tid < 16 && t > 0) {
                float cs = 0.f;
                for (int s2 = 0; s2 < 32; s2++) cs += cp[s2 * 16 + tid];
                c_l[tid] = cs;
            }
            __syncthreads();
            if (t > 0) {
                float v = wsum * SCALE;
                float mx = v;
                for (int d2 = 1; d2 < 16; d2 <<= 1) mx = fmaxf(mx, __shfl_xor(mx, d2, 16));
                float e = __expf(v - mx);
                float sm = e;
                for (int d2 = 1; d2 < 16; d2 <<= 1) sm += __shfl_xor(sm, d2, 16);
                wa = e / sm;
                rs = (1.f - wa) * asum + wa * c_l[bi];
            } else {
                rs = asum;
            }
            wa_l[tid] = wa;
            float v = rs * SCALE;
            float mx = v;
            for (int d2 = 1; d2 < 16; d2 <<= 1) mx = fmaxf(mx, __shfl_xor(mx, d2, 16));
            float e = __expf(v - mx);
            float sm = e;
            for (int d2 = 1; d2 < 16; d2 <<= 1) sm += __shfl_xor(sm, d2, 16);
            ra_l[tid] = e / sm;
        }
        __syncthreads();
        // lazy tape update (tape_{t-2} -> tape_{t-1}) then read_val
        if (t > 0) {
            for (int j = 0; j < 32; j++) {
                int bn = gi + (j << 3);
                float wv2 = wa_l[bn];
                tape_l[bn * 33 + ci] = (1.f - wv2) * tape_l[bn * 33 + ci] + wv2 * wv_l[(bn >> 4) * 33 + ci];
            }
        }
        __syncthreads();
        for (int j = 0; j < 2; j++) {
            int b2 = gi + (j << 3);
            float a2 = 0.f;
            for (int n2 = 0; n2 < 16; n2++) a2 += ra_l[b2 * 16 + n2] * tape_l[(b2 * 16 + n2) * 33 + ci];
            rv_l[b2 * 33 + ci] = a2;
        }
        // stage h_{t-1} (buffer t&1) into LDS
        {
            const _Float16* hsrc = hg + (size_t)(t & 1) * 16384;
            for (int j = 0; j < 8; j++) {
                int flat = j * 2048 + tid * 8;
                *(half8*)(&h_l[(flat >> 10) * 1032 + (flat & 1023)]) = *(const half8*)(&hsrc[flat]);
            }
        }
        __syncthreads();
        // MFMA: W_h slice x h_{t-1}; K split over 4 waves
        {
            f32x4 a0 = (f32x4){0.f, 0.f, 0.f, 0.f}, a1 = (f32x4){0.f, 0.f, 0.f, 0.f};
            const int row = lane & 15, q = lane >> 4, kb = w * 256;
            #pragma unroll
            for (int kk = 0; kk < 8; kk++) {
                half8 af = *(const half8*)(&h_l[row * 1032 + kb + kk * 32 + q * 8]);
                a0 = __builtin_amdgcn_mfma_f32_16x16x32_f16(af, whf[0][kk], a0, 0, 0, 0);
                a1 = __builtin_amdgcn_mfma_f32_16x16x32_f16(af, whf[1][kk], a1, 0, 0, 0);
            }
            *(f32x4*)(&red_l[(w * 2 + 0) * 256 + lane * 4]) = a0;
            *(f32x4*)(&red_l[(w * 2 + 1) * 256 + lane * 4]) = a1;
        }
        __syncthreads();
        // cross-wave reduce + epilogue (thread = (bi, ni))
        {
            const int quad = bi >> 2, reg = bi & 3, ln = quad * 16 + ni;
            _Float16* hdst = hg + (size_t)((t + 1) & 1) * 16384;
            #pragma unroll
            for (int nt = 0; nt < 2; nt++) {
                float v = red_l[(0 + nt) * 256 + ln * 4 + reg] + red_l[(2 + nt) * 256 + ln * 4 + reg]
                        + red_l[(4 + nt) * 256 + ln * 4 + reg] + red_l[(6 + nt) * 256 + ln * 4 + reg];
                int cc = nt * 16 + ni, gc = s * 32 + cc;
                size_t m = (size_t)bi * 512 + t;
                float rv2 = rv_l[bi * 33 + cc];
                float xp = (float)xz[m * 2048 + gc];
                float zz = (float)xz[m * 2048 + 1024 + gc];
                float hv = tanhf(v + xp + rv2 + bh[gc]);
                float g2 = zz + rv2 + hv;
                float sg = 1.f / (1.f + __expf(-g2));
                out[m * 1024 + gc] = hv * g2 * sg;
                hn_l[bi * 33 + cc] = hv;
                hdst[(size_t)bi * 1024 + gc] = (_Float16)hv;
            }
        }
        __threadfence();
        __syncthreads();
        if (tid == 0) __hip_atomic_store(&tag_p1[s], (unsigned)(t + 1), __ATOMIC_RELEASE, __HIP_MEMORY_SCOPE_AGENT);

        // ================= Phase 2: wv_t, score partials =================
        if (tid < 32) {
            while (__hip_atomic_load(&tag_p1[tid], __ATOMIC_RELAXED, __HIP_MEMORY_SCOPE_AGENT) < (unsigned)(t + 1))
                __builtin_amdgcn_s_sleep(1);
        }
        __syncthreads();
        __threadfence();
        // stage h_t (buffer (t+1)&1)
        {
            const _Float16* hsrc = hg + (size_t)((t + 1) & 1) * 16384;
            for (int j = 0; j < 8; j++) {
                int flat = j * 2048 + tid * 8;
                *(half8*)(&h_l[(flat >> 10) * 1032 + (flat & 1023)]) = *(const half8*)(&hsrc[flat]);
            }
        }
        __syncthreads();
        {
            f32x4 a0 = (f32x4){0.f, 0.f, 0.f, 0.f}, a1 = (f32x4){0.f, 0.f, 0.f, 0.f};
            const int row = lane & 15, q = lane >> 4, kb = w * 256;
            #pragma unroll
            for (int kk = 0; kk < 8; kk++) {
                half8 af = *(const half8*)(&h_l[row * 1032 + kb + kk * 32 + q * 8]);
                a0 = __builtin_amdgcn_mfma_f32_16x16x32_f16(af, wwf[0][kk], a0, 0, 0, 0);
                a1 = __builtin_amdgcn_mfma_f32_16x16x32_f16(af, wwf[1][kk], a1, 0, 0, 0);
            }
            *(f32x4*)(&red_l[(w * 2 + 0) * 256 + lane * 4]) = a0;
            *(f32x4*)(&red_l[(w * 2 + 1) * 256 + lane * 4]) = a1;
        }
        __syncthreads();
        {
            const int quad = bi >> 2, reg = bi & 3, ln = quad * 16 + ni;
            #pragma unroll
            for (int nt = 0; nt < 2; nt++) {
                float v = red_l[(0 + nt) * 256 + ln * 4 + reg] + red_l[(2 + nt) * 256 + ln * 4 + reg]
                        + red_l[(4 + nt) * 256 + ln * 4 + reg] + red_l[(6 + nt) * 256 + ln * 4 + reg];
                wv_l[bi * 33 + nt * 16 + ni] = v;
            }
        }
        __syncthreads();
        // partial dots over this block's 32 columns (thread = (bi, ni))
        {
            float ws2 = 0.f, aa = 0.f;
            for (int c2 = 0; c2 < 32; c2++) {
                float tp = tape_l[tid * 33 + c2];
                ws2 += wv_l[bi * 33 + c2] * tp;
                aa += hn_l[bi * 33 + c2] * tp;
            }
            wsp[s * 256 + tid] = ws2;
            ap[s * 256 + tid] = aa;
            if (tid < 16) {
                float cs = 0.f;
                for (int c2 = 0; c2 < 32; c2++) cs += hn_l[tid * 33 + c2] * wv_l[tid * 33 + c2];
                cp[s * 16 + tid] = cs;
            }
        }
        __threadfence();
        __syncthreads();
        if (tid == 0) __hip_atomic_store(&tag_p2[s], (unsigned)(t + 2), __ATOMIC_RELEASE, __HIP_MEMORY_SCOPE_AGENT);
    }
    // ================= finale: apply last tape update, write h_tape_final =================
    if (tid < 32) {
        while (__hip_atomic_load(&tag_p2[tid], __ATOMIC_RELAXED, __HIP_MEMORY_SCOPE_AGENT) < 513u)
            __builtin_amdgcn_s_sleep(1);
    }
    __syncthreads();
    __threadfence();
    {
        float wsum = 0.f;
        for (int s2 = 0; s2 < 32; s2++) wsum += wsp[s2 * 256 + tid];
        float v = wsum * SCALE;
        float mx = v;
        for (int d2 = 1; d2 < 16; d2 <<= 1) mx = fmaxf(mx, __shfl_xor(mx, d2, 16));
        float e = __expf(v - mx);
        float sm = e;
        for (int d2 = 1; d2 < 16; d2 <<= 1) sm += __shfl_xor(sm, d2, 16);
        wa_l[tid] = e / sm;
    }
    __syncthreads();
    for (int j = 0; j < 32; j++) {
        int bn = gi + (j << 3);
        float wv2 = wa_l[bn];
        float tf = (1.f - wv2) * tape_l[bn * 33 + ci] + wv2 * wv_l[(bn >> 4) * 33 + ci];
        out[8388608ULL + (size_t)bn * 1024 + s * 32 + ci] = tf;
    }
}

extern "C" void kernel_launch(void* const* d_in, const int* in_sizes, int n_in,
                              void* d_out, int out_size, void* d_ws, size_t ws_size,
                              hipStream_t stream) {
    const float* x     = (const float*)d_in[0];  // [16][512][1024]
    const float* tape0 = (const float*)d_in[1];  // [16][16][1024]
    const float* h0    = (const float*)d_in[2];  // [16][1024]
    const float* Wh    = (const float*)d_in[3];  // [1024][1024]
    const float* Wxz   = (const float*)d_in[4];  // [2048][1024]
    const float* bh    = (const float*)d_in[5];  // [1024]
    const float* Ww    = (const float*)d_in[6];  // [1024][1024]

    char* ws = (char*)d_ws;
    _Float16* xbf   = (_Float16*)(ws + XBF_OFF);
    _Float16* wxzbf = (_Float16*)(ws + WXZ_OFF);
    _Float16* whbf  = (_Float16*)(ws + WH_OFF);
    _Float16* wwbf  = (_Float16*)(ws + WW_OFF);
    _Float16* xzbf  = (_Float16*)(ws + XZ_OFF);
    _Float16* hg    = (_Float16*)(ws + HG_OFF);
    float* wsp      = (float*)(ws + WSP_OFF);
    float* ap       = (float*)(ws + AP_OFF);
    float* cp       = (float*)(ws + CP_OFF);
    unsigned* tags  = (unsigned*)(ws + TAG_OFF);

    hipMemsetAsync(ws + TAG_OFF, 0, 256, stream);

    cvt_kernel<<<8192, 256, 0, stream>>>(x, xbf, 2097152);
    cvt_kernel<<<2048, 256, 0, stream>>>(Wxz, wxzbf, 524288);
    cvt_kernel<<<1024, 256, 0, stream>>>(Wh, whbf, 262144);
    cvt_kernel<<<1024, 256, 0, stream>>>(Ww, wwbf, 262144);

    gemm_xz<<<dim3(16, 64), 256, 0, stream>>>(xbf, wxzbf, xzbf);

    scan_kernel<<<32, 256, 0, stream>>>(xzbf, tape0, h0, bh, whbf, wwbf,
                                        hg, wsp, ap, cp, tags, (float*)d_out);
}

// Round 2
// 9708.414 us; speedup vs baseline: 1.6576x; 1.6576x over previous
//
#include <hip/hip_runtime.h>

typedef _Float16 half8 __attribute__((ext_vector_type(8)));
typedef _Float16 half4_t __attribute__((ext_vector_type(4)));
typedef float f32x4 __attribute__((ext_vector_type(4)));
typedef unsigned long long u64;

#define SCALE 0.03125f   // 1/sqrt(1024)

// workspace layout (bytes)
#define XZ_OFF   0ULL            // f16 [8192][2048]  33,554,432
#define XBF_OFF  33554432ULL     // f16 [8192][1024]  16,777,216
#define WXZ_OFF  50331648ULL     // f16 [2048][1024]   4,194,304
#define WH_OFF   54525952ULL     // f16 [1024][1024]   2,097,152
#define WW_OFF   56623104ULL     // f16 [1024][1024]   2,097,152
#define HG_OFF   58720256ULL     // u64 [2][16][256]      65,536 (h double buffer, 4xf16 per u64)
#define PAP_OFF  58785792ULL     // u64 [32][256]         65,536 (packed {A,W} partials)
#define CP_OFF   58851328ULL     // f32 [32][16]           2,048
#define TAG_OFF  58853376ULL     // u32 [2][32]              256

#define AT_LD(p)   __hip_atomic_load((p), __ATOMIC_RELAXED, __HIP_MEMORY_SCOPE_AGENT)
#define AT_ST(p,v) __hip_atomic_store((p), (v), __ATOMIC_RELAXED, __HIP_MEMORY_SCOPE_AGENT)

union PackF2 { u64 u; float f[2]; };
union PackH4 { u64 u; half4_t h; };

__global__ void cvt_kernel(const float* __restrict__ in, _Float16* __restrict__ o, int n4) {
    int i = blockIdx.x * 256 + threadIdx.x;
    if (i < n4) {
        f32x4 v = ((const f32x4*)in)[i];
        half4_t h;
        h[0] = (_Float16)v[0]; h[1] = (_Float16)v[1];
        h[2] = (_Float16)v[2]; h[3] = (_Float16)v[3];
        ((half4_t*)o)[i] = h;
    }
}

// xz[m][n] = sum_k x[m][k] * Wxz[n][k];  M=8192, N=2048, K=1024
__launch_bounds__(256, 1)
__global__ void gemm_xz(const _Float16* __restrict__ A,   // [8192][1024]
                        const _Float16* __restrict__ Bw,  // [2048][1024]
                        _Float16* __restrict__ C) {       // [8192][2048]
    __shared__ _Float16 As[128 * 40];
    __shared__ _Float16 Bs[128 * 40];
    const int tid = threadIdx.x;
    const int m0 = blockIdx.y * 128, n0 = blockIdx.x * 128;
    const int w = tid >> 6, lane = tid & 63;
    const int mw = (w >> 1) * 64, nw = (w & 1) * 64;
    const int row = lane & 15, q = lane >> 4;
    f32x4 acc[4][4];
    #pragma unroll
    for (int mt = 0; mt < 4; mt++)
        #pragma unroll
        for (int nt = 0; nt < 4; nt++)
            acc[mt][nt] = (f32x4){0.f, 0.f, 0.f, 0.f};

    for (int k0 = 0; k0 < 1024; k0 += 32) {
        __syncthreads();
        for (int cc = tid; cc < 512; cc += 256) {
            int r = cc >> 2, kc = (cc & 3) * 8;
            *(half8*)(&As[r * 40 + kc]) = *(const half8*)(&A[(size_t)(m0 + r) * 1024 + k0 + kc]);
            *(half8*)(&Bs[r * 40 + kc]) = *(const half8*)(&Bw[(size_t)(n0 + r) * 1024 + k0 + kc]);
        }
        __syncthreads();
        half8 af[4], bf[4];
        #pragma unroll
        for (int mt = 0; mt < 4; mt++) af[mt] = *(const half8*)(&As[(mw + mt * 16 + row) * 40 + q * 8]);
        #pragma unroll
        for (int nt = 0; nt < 4; nt++) bf[nt] = *(const half8*)(&Bs[(nw + nt * 16 + row) * 40 + q * 8]);
        #pragma unroll
        for (int mt = 0; mt < 4; mt++)
            #pragma unroll
            for (int nt = 0; nt < 4; nt++)
                acc[mt][nt] = __builtin_amdgcn_mfma_f32_16x16x32_f16(af[mt], bf[nt], acc[mt][nt], 0, 0, 0);
    }
    #pragma unroll
    for (int mt = 0; mt < 4; mt++)
        #pragma unroll
        for (int nt = 0; nt < 4; nt++)
            #pragma unroll
            for (int r = 0; r < 4; r++) {
                int gm = m0 + mw + mt * 16 + q * 4 + r;
                int gn = n0 + nw + nt * 16 + row;
                C[(size_t)gm * 2048 + gn] = (_Float16)acc[mt][nt][r];
            }
}

// Persistent scan: 32 blocks, block s owns columns [s*32, s*32+32) for all 16 batches.
// All cross-block traffic via relaxed agent-scope atomics (sc0 sc1 -> MALL-coherent,
// no buffer_wbl2/buffer_inv L2 walks). Tags: relaxed store after __syncthreads
// (barrier drains vmcnt -> sc1 data stores are at the coherence point first).
__launch_bounds__(256, 1)
__global__ void scan_kernel(const _Float16* __restrict__ xz,   // [8192][2048]
                            const float* __restrict__ tape_in, // [16][16][1024]
                            const float* __restrict__ h_in,    // [16][1024]
                            const float* __restrict__ bh,      // [1024]
                            const _Float16* __restrict__ wh,   // [1024][1024]
                            const _Float16* __restrict__ ww,   // [1024][1024]
                            u64* __restrict__ hg,              // [2][16][256] u64 (4 f16 each)
                            u64* __restrict__ pap,             // [32][256] {A,W} partial pairs
                            float* __restrict__ cp,            // [32][16]
                            unsigned* __restrict__ tags,       // [2][32]
                            float* __restrict__ out) {
    __shared__ _Float16 h_l[16 * 1032];
    __shared__ float tape_l[256 * 33];
    __shared__ float wv_l[16 * 33];
    __shared__ float hn_l[16 * 33];
    __shared__ float rv_l[16 * 33];
    __shared__ float red_l[8 * 256];
    __shared__ float wa_l[256], ra_l[256], c_l[16];

    const int tid = threadIdx.x, s = blockIdx.x;
    const int w = tid >> 6, lane = tid & 63;
    const int bi = tid >> 4, ni = tid & 15;   // (batch, slot) mapping
    const int ci = tid & 31, gi = tid >> 5;   // (col, group) mapping
    unsigned* tag_p1 = tags;
    unsigned* tag_p2 = tags + 32;

    // ---- W fragment preload (pinned in VGPRs for all 512 steps) ----
    half8 whf[2][8], wwf[2][8];
    {
        const int fr = lane & 15, fq = lane >> 4;
        #pragma unroll
        for (int nt = 0; nt < 2; nt++)
            #pragma unroll
            for (int kk = 0; kk < 8; kk++) {
                int gcol = s * 32 + nt * 16 + fr;
                int gk = w * 256 + kk * 32 + fq * 8;
                whf[nt][kk] = *(const half8*)(&wh[(size_t)gcol * 1024 + gk]);
                wwf[nt][kk] = *(const half8*)(&ww[(size_t)gcol * 1024 + gk]);
            }
    }
    // ---- prologue: tape slice -> LDS, publish h_init (buffer 0), A partials ----
    for (int j = 0; j < 32; j++) {
        int bn = gi + (j << 3);
        tape_l[bn * 33 + ci] = tape_in[(size_t)bn * 1024 + s * 32 + ci];
    }
    if (tid < 128) {
        int b = tid >> 3, seg = tid & 7;
        PackH4 pk;
        #pragma unroll
        for (int k = 0; k < 4; k++)
            pk.h[k] = (_Float16)h_in[(size_t)b * 1024 + s * 32 + seg * 4 + k];
        AT_ST(&hg[b * 256 + s * 8 + seg], pk.u);
    }
    __syncthreads();
    {
        float asum = 0.f;
        for (int c2 = 0; c2 < 32; c2++)
            asum += h_in[(size_t)bi * 1024 + s * 32 + c2] * tape_l[tid * 33 + c2];
        PackF2 pk; pk.f[0] = asum; pk.f[1] = 0.f;
        AT_ST(&pap[s * 256 + tid], pk.u);
    }
    __syncthreads();
    if (tid == 0) AT_ST(&tag_p2[s], 1u);

    const float bh0 = bh[s * 32 + ni], bh1 = bh[s * 32 + 16 + ni];

    for (int t = 0; t < 512; t++) {
        // ================= Phase 1: h_t, out_t =================
        // prefetch h_{t-1} into LDS (gated by previous step's tag_p1 wait, not this one)
        if (t > 0) {
            const u64* hsrc = hg + (size_t)(t & 1) * 4096;
            #pragma unroll
            for (int j = 0; j < 16; j++) {
                int idx = j * 256 + tid;
                PackH4 cv; cv.u = AT_LD(&hsrc[idx]);
                *(half4_t*)(&h_l[(idx >> 8) * 1032 + (idx & 255) * 4]) = cv.h;
            }
        }
        // prefetch xz operands for the epilogue (pure streaming, no gating)
        const size_t mrow = ((size_t)bi * 512 + t) * 2048;
        const float xp0 = (float)xz[mrow + s * 32 + ni];
        const float xp1 = (float)xz[mrow + s * 32 + 16 + ni];
        const float zz0 = (float)xz[mrow + 1024 + s * 32 + ni];
        const float zz1 = (float)xz[mrow + 1024 + s * 32 + 16 + ni];

        if (tid < 32) {
            while (AT_LD(&tag_p2[tid]) < (unsigned)(t + 1))
                __builtin_amdgcn_s_sleep(1);
        }
        __syncthreads();
        if (t == 0) {  // h_0 publish is gated by tag_p2 itself; stage after the wait
            const u64* hsrc = hg;
            #pragma unroll
            for (int j = 0; j < 16; j++) {
                int idx = j * 256 + tid;
                PackH4 cv; cv.u = AT_LD(&hsrc[idx]);
                *(half4_t*)(&h_l[(idx >> 8) * 1032 + (idx & 255) * 4]) = cv.h;
            }
        }

        // scalar stage: sum partials, softmaxes (thread = (batch bi, slot ni))
        float wa = 0.f, rs;
        {
            float wsum = 0.f, asum = 0.f;
            #pragma unroll
            for (int s2 = 0; s2 < 32; s2++) {
                PackF2 pk; pk.u = AT_LD(&pap[s2 * 256 + tid]);
                asum += pk.f[0]; wsum += pk.f[1];
            }
            if (tid < 16 && t > 0) {
                float cs = 0.f;
                #pragma unroll
                for (int s2 = 0; s2 < 32; s2++) cs += AT_LD(&cp[s2 * 16 + tid]);
                c_l[tid] = cs;
            }
            __syncthreads();
            if (t > 0) {
                float v = wsum * SCALE;
                float mx = v;
                for (int d2 = 1; d2 < 16; d2 <<= 1) mx = fmaxf(mx, __shfl_xor(mx, d2, 16));
                float e = __expf(v - mx);
                float sm = e;
                for (int d2 = 1; d2 < 16; d2 <<= 1) sm += __shfl_xor(sm, d2, 16);
                wa = e / sm;
                rs = (1.f - wa) * asum + wa * c_l[bi];
            } else {
                rs = asum;
            }
            wa_l[tid] = wa;
            float v = rs * SCALE;
            float mx = v;
            for (int d2 = 1; d2 < 16; d2 <<= 1) mx = fmaxf(mx, __shfl_xor(mx, d2, 16));
            float e = __expf(v - mx);
            float sm = e;
            for (int d2 = 1; d2 < 16; d2 <<= 1) sm += __shfl_xor(sm, d2, 16);
            ra_l[tid] = e / sm;
        }
        __syncthreads();
        // lazy tape update (tape_{t-2} -> tape_{t-1}) then read_val
        if (t > 0) {
            for (int j = 0; j < 32; j++) {
                int bn = gi + (j << 3);
                float wv2 = wa_l[bn];
                tape_l[bn * 33 + ci] = (1.f - wv2) * tape_l[bn * 33 + ci] + wv2 * wv_l[(bn >> 4) * 33 + ci];
            }
        }
        __syncthreads();
        for (int j = 0; j < 2; j++) {
            int b2 = gi + (j << 3);
            float a2 = 0.f;
            for (int n2 = 0; n2 < 16; n2++) a2 += ra_l[b2 * 16 + n2] * tape_l[(b2 * 16 + n2) * 33 + ci];
            rv_l[b2 * 33 + ci] = a2;
        }
        __syncthreads();
        // MFMA: W_h slice x h_{t-1}; K split over 4 waves
        {
            f32x4 a0 = (f32x4){0.f, 0.f, 0.f, 0.f}, a1 = (f32x4){0.f, 0.f, 0.f, 0.f};
            const int row = lane & 15, q = lane >> 4, kb = w * 256;
            #pragma unroll
            for (int kk = 0; kk < 8; kk++) {
                half8 af = *(const half8*)(&h_l[row * 1032 + kb + kk * 32 + q * 8]);
                a0 = __builtin_amdgcn_mfma_f32_16x16x32_f16(af, whf[0][kk], a0, 0, 0, 0);
                a1 = __builtin_amdgcn_mfma_f32_16x16x32_f16(af, whf[1][kk], a1, 0, 0, 0);
            }
            *(f32x4*)(&red_l[(w * 2 + 0) * 256 + lane * 4]) = a0;
            *(f32x4*)(&red_l[(w * 2 + 1) * 256 + lane * 4]) = a1;
        }
        __syncthreads();
        // cross-wave reduce + epilogue (thread = (bi, ni))
        {
            const int quad = bi >> 2, reg = bi & 3, ln = quad * 16 + ni;
            #pragma unroll
            for (int nt = 0; nt < 2; nt++) {
                float v = red_l[(0 + nt) * 256 + ln * 4 + reg] + red_l[(2 + nt) * 256 + ln * 4 + reg]
                        + red_l[(4 + nt) * 256 + ln * 4 + reg] + red_l[(6 + nt) * 256 + ln * 4 + reg];
                int cc = nt * 16 + ni, gc = s * 32 + cc;
                size_t m = (size_t)bi * 512 + t;
                float rv2 = rv_l[bi * 33 + cc];
                float xp = nt ? xp1 : xp0;
                float zz = nt ? zz1 : zz0;
                float bb = nt ? bh1 : bh0;
                float hv = tanhf(v + xp + rv2 + bb);
                float g2 = zz + rv2 + hv;
                float sg = 1.f / (1.f + __expf(-g2));
                out[m * 1024 + gc] = hv * g2 * sg;
                hn_l[bi * 33 + cc] = hv;
            }
        }
        __syncthreads();
        // publish h_t (packed f16x4 via MALL-coherent atomics)
        if (tid < 128) {
            u64* hdst = hg + (size_t)((t + 1) & 1) * 4096;
            int b = tid >> 3, seg = tid & 7;
            PackH4 pk;
            #pragma unroll
            for (int k = 0; k < 4; k++)
                pk.h[k] = (_Float16)hn_l[b * 33 + seg * 4 + k];
            AT_ST(&hdst[b * 256 + s * 8 + seg], pk.u);
        }
        __syncthreads();
        if (tid == 0) AT_ST(&tag_p1[s], (unsigned)(t + 1));

        // ================= Phase 2: wv_t, score partials =================
        if (tid < 32) {
            while (AT_LD(&tag_p1[tid]) < (unsigned)(t + 1))
                __builtin_amdgcn_s_sleep(1);
        }
        __syncthreads();
        // stage h_t (buffer (t+1)&1)
        {
            const u64* hsrc = hg + (size_t)((t + 1) & 1) * 4096;
            #pragma unroll
            for (int j = 0; j < 16; j++) {
                int idx = j * 256 + tid;
                PackH4 cv; cv.u = AT_LD(&hsrc[idx]);
                *(half4_t*)(&h_l[(idx >> 8) * 1032 + (idx & 255) * 4]) = cv.h;
            }
        }
        __syncthreads();
        {
            f32x4 a0 = (f32x4){0.f, 0.f, 0.f, 0.f}, a1 = (f32x4){0.f, 0.f, 0.f, 0.f};
            const int row = lane & 15, q = lane >> 4, kb = w * 256;
            #pragma unroll
            for (int kk = 0; kk < 8; kk++) {
                half8 af = *(const half8*)(&h_l[row * 1032 + kb + kk * 32 + q * 8]);
                a0 = __builtin_amdgcn_mfma_f32_16x16x32_f16(af, wwf[0][kk], a0, 0, 0, 0);
                a1 = __builtin_amdgcn_mfma_f32_16x16x32_f16(af, wwf[1][kk], a1, 0, 0, 0);
            }
            *(f32x4*)(&red_l[(w * 2 + 0) * 256 + lane * 4]) = a0;
            *(f32x4*)(&red_l[(w * 2 + 1) * 256 + lane * 4]) = a1;
        }
        __syncthreads();
        {
            const int quad = bi >> 2, reg = bi & 3, ln = quad * 16 + ni;
            #pragma unroll
            for (int nt = 0; nt < 2; nt++) {
                float v = red_l[(0 + nt) * 256 + ln * 4 + reg] + red_l[(2 + nt) * 256 + ln * 4 + reg]
                        + red_l[(4 + nt) * 256 + ln * 4 + reg] + red_l[(6 + nt) * 256 + ln * 4 + reg];
                wv_l[bi * 33 + nt * 16 + ni] = v;
            }
        }
        __syncthreads();
        // partial dots over this block's 32 columns (thread = (bi, ni))
        {
            float ws2 = 0.f, aa = 0.f;
            for (int c2 = 0; c2 < 32; c2++) {
                float tp = tape_l[tid * 33 + c2];
                ws2 += wv_l[bi * 33 + c2] * tp;
                aa += hn_l[bi * 33 + c2] * tp;
            }
            PackF2 pk; pk.f[0] = aa; pk.f[1] = ws2;
            AT_ST(&pap[s * 256 + tid], pk.u);
            if (tid < 16) {
                float cs = 0.f;
                for (int c2 = 0; c2 < 32; c2++) cs += hn_l[tid * 33 + c2] * wv_l[tid * 33 + c2];
                AT_ST(&cp[s * 16 + tid], cs);
            }
        }
        __syncthreads();
        if (tid == 0) AT_ST(&tag_p2[s], (unsigned)(t + 2));
    }
    // ================= finale: apply last tape update, write h_tape_final =================
    if (tid < 32) {
        while (AT_LD(&tag_p2[tid]) < 513u)
            __builtin_amdgcn_s_sleep(1);
    }
    __syncthreads();
    {
        float wsum = 0.f;
        #pragma unroll
        for (int s2 = 0; s2 < 32; s2++) {
            PackF2 pk; pk.u = AT_LD(&pap[s2 * 256 + tid]);
            wsum += pk.f[1];
        }
        float v = wsum * SCALE;
        float mx = v;
        for (int d2 = 1; d2 < 16; d2 <<= 1) mx = fmaxf(mx, __shfl_xor(mx, d2, 16));
        float e = __expf(v - mx);
        float sm = e;
        for (int d2 = 1; d2 < 16; d2 <<= 1) sm += __shfl_xor(sm, d2, 16);
        wa_l[tid] = e / sm;
    }
    __syncthreads();
    for (int j = 0; j < 32; j++) {
        int bn = gi + (j << 3);
        float wv2 = wa_l[bn];
        float tf = (1.f - wv2) * tape_l[bn * 33 + ci] + wv2 * wv_l[(bn >> 4) * 33 + ci];
        out[8388608ULL + (size_t)bn * 1024 + s * 32 + ci] = tf;
    }
}

extern "C" void kernel_launch(void* const* d_in, const int* in_sizes, int n_in,
                              void* d_out, int out_size, void* d_ws, size_t ws_size,
                              hipStream_t stream) {
    const float* x     = (const float*)d_in[0];  // [16][512][1024]
    const float* tape0 = (const float*)d_in[1];  // [16][16][1024]
    const float* h0    = (const float*)d_in[2];  // [16][1024]
    const float* Wh    = (const float*)d_in[3];  // [1024][1024]
    const float* Wxz   = (const float*)d_in[4];  // [2048][1024]
    const float* bh    = (const float*)d_in[5];  // [1024]
    const float* Ww    = (const float*)d_in[6];  // [1024][1024]

    char* ws = (char*)d_ws;
    _Float16* xbf   = (_Float16*)(ws + XBF_OFF);
    _Float16* wxzbf = (_Float16*)(ws + WXZ_OFF);
    _Float16* whbf  = (_Float16*)(ws + WH_OFF);
    _Float16* wwbf  = (_Float16*)(ws + WW_OFF);
    _Float16* xzbf  = (_Float16*)(ws + XZ_OFF);
    u64* hg         = (u64*)(ws + HG_OFF);
    u64* pap        = (u64*)(ws + PAP_OFF);
    float* cp       = (float*)(ws + CP_OFF);
    unsigned* tags  = (unsigned*)(ws + TAG_OFF);

    hipMemsetAsync(ws + TAG_OFF, 0, 256, stream);

    cvt_kernel<<<8192, 256, 0, stream>>>(x, xbf, 2097152);
    cvt_kernel<<<2048, 256, 0, stream>>>(Wxz, wxzbf, 524288);
    cvt_kernel<<<1024, 256, 0, stream>>>(Wh, whbf, 262144);
    cvt_kernel<<<1024, 256, 0, stream>>>(Ww, wwbf, 262144);

    gemm_xz<<<dim3(16, 64), 256, 0, stream>>>(xbf, wxzbf, xzbf);

    scan_kernel<<<32, 256, 0, stream>>>(xzbf, tape0, h0, bh, whbf, wwbf,
                                        hg, pap, cp, tags, (float*)d_out);
}